// Round 8
// baseline (38024.860 us; speedup 1.0000x reference)
//
#include <hip/hip_runtime.h>

// PGN decoder: B=32, L=400, T=40 steps, H=A=512, E=256, V=32000, oov=50.
// Outputs (flat in d_out, fp32): final (40,32,32050) | attns (40,32,400) |
// covs (40,32,400) | h_f (32,512) | ctx_f (32,512) | pgens (40,32)
//
// Structure: prologue + round-0 pre-decode dispatches, then ONE persistent kernel
// (REGULAR launch, 512 blocks = 2/CU co-resident by capacity) running the 40-step
// decode loop with a fence-hardened self-managed grid barrier.
// (hipLaunchCooperativeKernel is dropped under the harness's graph capture —
//  r1/r5/r6 "3.64e-2" failures were all-zero outputs from a never-run mega.)
#define BB 32
#define LL 400
#define TT 40
#define HH 512
#define VV 32000
#define VEXT 32050
#define NBLK 512

typedef __attribute__((ext_vector_type(8))) short bf16x8;
typedef __attribute__((ext_vector_type(4))) float f32x4;
typedef __attribute__((ext_vector_type(2))) float f32x2;

__device__ __forceinline__ float bf2f(unsigned short u){
  union { unsigned int i; float f; } v; v.i = ((unsigned int)u) << 16; return v.f;
}
__device__ __forceinline__ unsigned short f2bf(float f){
  union { float f; unsigned int i; } v; v.f = f;
  unsigned int i = v.i;
  return (unsigned short)((i + 0x7FFFu + ((i >> 16) & 1u)) >> 16); // RNE
}
__device__ __forceinline__ float fast_tanh(float x){
  x = fminf(20.f, fmaxf(-20.f, x));
  float e = __expf(2.f * x);
  return (e - 1.f) * __builtin_amdgcn_rcpf(e + 1.f);
}
__device__ __forceinline__ float fast_sigmoid(float x){
  x = fminf(30.f, fmaxf(-30.f, x));
  return __builtin_amdgcn_rcpf(1.f + __expf(-x));
}

// ---------------- P0: weight transposes (f32 -> bf16 NxK) + converts + pgen_emb ----------------
__device__ void transpose_bf16(const float* __restrict__ in, unsigned short* __restrict__ out,
                               int R, int C, int tile, float (*t)[65]){
  int tcn = C >> 6;
  int tr = tile / tcn, tc = tile - tr * tcn;
  int r0 = tr << 6, c0 = tc << 6;
  int cc = threadIdx.x & 63, rb = threadIdx.x >> 6;
  #pragma unroll
  for (int p = 0; p < 16; p++){
    int r = rb + p * 4;
    t[r][cc] = in[(size_t)(r0 + r) * C + (c0 + cc)];
  }
  __syncthreads();
  #pragma unroll
  for (int p = 0; p < 16; p++){
    int r = rb + p * 4;
    out[(size_t)(c0 + r) * R + (r0 + cc)] = f2bf(t[cc][r]);
  }
}

__global__ __launch_bounds__(256) void k_prep(
    const float* __restrict__ Wout, const float* __restrict__ Wg, const float* __restrict__ Ug,
    const float* __restrict__ W1, const float* __restrict__ W2, const float* __restrict__ enc,
    const float* __restrict__ dec_hidden, const int* __restrict__ dec_inp,
    const float* __restrict__ embedding, const float* __restrict__ Wp,
    unsigned short* WoutT, unsigned short* WgT, unsigned short* UgT,
    unsigned short* W1T, unsigned short* W2T, unsigned short* enc_bf,
    float* h0, unsigned short* h_bf, float* pgen_emb, unsigned* bar)
{
  __shared__ float tls[64][65];
  int b = blockIdx.x;
  int tid = threadIdx.x;
  if (b == 0 && tid < 64) bar[tid] = 0u;  // zero grid-barrier state for k_mega
  if (b < 4000){ transpose_bf16(Wout, WoutT, 512, 32000, b, tls); return; }
  b -= 4000;
  if (b < 288){ transpose_bf16(Wg, WgT, 768, 1536, b, tls); return; }
  b -= 288;
  if (b < 192){ transpose_bf16(Ug, UgT, 512, 1536, b, tls); return; }
  b -= 192;
  if (b < 64){ transpose_bf16(W1, W1T, 512, 512, b, tls); return; }
  b -= 64;
  if (b < 64){ transpose_bf16(W2, W2T, 512, 512, b, tls); return; }
  b -= 64;
  if (b < 3200){
    size_t i0 = (size_t)b * 2048 + tid;
    #pragma unroll
    for (int p = 0; p < 8; p++){ size_t i = i0 + p * 256; enc_bf[i] = f2bf(enc[i]); }
    return;
  }
  b -= 3200;
  if (b < 8){ // h0 = dec_hidden (f32 + bf16 copies)
    size_t i0 = (size_t)b * 2048 + tid;
    #pragma unroll
    for (int p = 0; p < 8; p++){
      size_t i = i0 + p * 256; float v = dec_hidden[i];
      h0[i] = v; h_bf[i] = f2bf(v);
    }
    return;
  }
  b -= 8;
  { // 40 blocks: pgen_emb[t][b] = emb(t,b) . Wp[1024:1280]
    int t = b;
    int bb = tid >> 3, l8 = tid & 7;
    int tok = dec_inp[bb * 41 + t];
    const float* e = embedding + (size_t)tok * 256 + l8 * 32;
    const float* wp = Wp + 1024 + l8 * 32;
    float p = 0.f;
    #pragma unroll
    for (int j = 0; j < 32; j++) p += e[j] * wp[j];
    p += __shfl_xor(p, 1); p += __shfl_xor(p, 2); p += __shfl_xor(p, 4);
    if (l8 == 0) pgen_emb[t * 32 + bb] = p;
  }
}

// ---------------- P1: embW[t,b,:] = emb(t,b) @ Wg[0:256,:] + bg   (all steps) ----------------
__global__ __launch_bounds__(256) void k_embw(
    const int* __restrict__ dec_inp, const float* __restrict__ embedding,
    const unsigned short* __restrict__ WgT, const float* __restrict__ bg,
    float* __restrict__ embW)
{
  __shared__ unsigned short as[64 * 264];
  int blk = blockIdx.x;         // 20 m-tiles x 24 n-tiles
  int bm = blk / 24, bn = blk - bm * 24;
  int m0 = bm * 64, n0 = bn * 64;
  int tid = threadIdx.x;
  for (int i = tid; i < 64 * 256; i += 256){
    int r = i >> 8, c = i & 255;
    int R = m0 + r; int t = R >> 5, bb = R & 31;
    int tok = dec_inp[bb * 41 + t];
    as[r * 264 + c] = f2bf(embedding[(size_t)tok * 256 + c]);
  }
  __syncthreads();
  int lane = tid & 63, w = tid >> 6;
  int l15 = lane & 15, quad = lane >> 4;
  const unsigned short* arow = as + (w * 16 + l15) * 264 + quad * 8;
  f32x4 acc[4];
  #pragma unroll
  for (int i = 0; i < 4; i++) acc[i] = (f32x4)0.0f;
  for (int k0 = 0; k0 < 256; k0 += 32){
    bf16x8 a = *(const bf16x8*)(arow + k0);
    #pragma unroll
    for (int nt = 0; nt < 4; nt++){
      const unsigned short* brow = WgT + (size_t)(n0 + nt * 16 + l15) * 768 + k0 + quad * 8;
      acc[nt] = __builtin_amdgcn_mfma_f32_16x16x32_bf16(a, *(const bf16x8*)brow, acc[nt], 0, 0, 0);
    }
  }
  #pragma unroll
  for (int nt = 0; nt < 4; nt++){
    int col = n0 + nt * 16 + l15;
    float bias = bg[col];
    #pragma unroll
    for (int r = 0; r < 4; r++){
      int row = m0 + w * 16 + quad * 4 + r;
      embW[(size_t)row * 1536 + col] = acc[nt][r] + bias;
    }
  }
}

// ---------------- P2: enc_feat = enc_output @ W2 + b2   (bf16 MFMA) ----------------
__global__ __launch_bounds__(256) void k_encfeat(
    const unsigned short* __restrict__ enc_bf, const unsigned short* __restrict__ W2T,
    const float* __restrict__ b2, unsigned short* __restrict__ ef_bf)
{
  int blk = blockIdx.x;            // 200 x 8
  int bm = blk >> 3, bn = blk & 7;
  int lane = threadIdx.x & 63, w = threadIdx.x >> 6;
  int l15 = lane & 15, quad = lane >> 4;
  int m0 = bm * 64 + w * 16;
  int n0 = bn * 64;
  const unsigned short* arow = enc_bf + (size_t)(m0 + l15) * 512 + quad * 8;
  f32x4 acc[4];
  #pragma unroll
  for (int i = 0; i < 4; i++) acc[i] = (f32x4)0.0f;
  for (int k0 = 0; k0 < 512; k0 += 32){
    bf16x8 a = *(const bf16x8*)(arow + k0);
    #pragma unroll
    for (int nt = 0; nt < 4; nt++){
      const unsigned short* brow = W2T + (size_t)(n0 + nt * 16 + l15) * 512 + k0 + quad * 8;
      acc[nt] = __builtin_amdgcn_mfma_f32_16x16x32_bf16(a, *(const bf16x8*)brow, acc[nt], 0, 0, 0);
    }
  }
  #pragma unroll
  for (int nt = 0; nt < 4; nt++){
    int col = n0 + nt * 16 + l15;
    float bias = b2[col];
    #pragma unroll
    for (int r = 0; r < 4; r++){
      int row = m0 + quad * 4 + r;
      ef_bf[(size_t)row * 512 + col] = f2bf(acc[nt][r] + bias);
    }
  }
}

// ========== round-0 standalone kernels for the PRE-decode state (verbatim) ==========

__global__ __launch_bounds__(256) void k_gemm_h(
    const unsigned short* __restrict__ h_bf,
    const unsigned short* __restrict__ WoutT, const float* __restrict__ bout, float* __restrict__ logits,
    const unsigned short* __restrict__ W1T, const float* __restrict__ b1, float* __restrict__ w1h,
    int nb_log, float* __restrict__ tilems,
    const int* __restrict__ eidx, const float* __restrict__ attn_prev,
    const float* __restrict__ pgens_prev, float* __restrict__ final_prev)
{
  int blk = blockIdx.x;
  int tid = threadIdx.x;
  if (blk >= nb_log + 8){ // scatter-add copy dist for PREVIOUS step
    int i = (blk - nb_log - 8) * 256 + tid;
    if (i >= 12800 || !final_prev) return;
    int b = i / 400;
    float wv = (1.f - pgens_prev[b]) * attn_prev[i];
    atomicAdd(final_prev + (size_t)b * VEXT + eidx[i], wv);
    return;
  }
  __shared__ unsigned short hs[32 * 520];
  __shared__ float smp[4][16][2];
  for (int i = tid; i < 8192; i += 256){
    int bb = i >> 8;
    int cp = (i & 255) * 2;
    *(unsigned int*)(hs + bb * 520 + cp) = *(const unsigned int*)(h_bf + bb * 512 + cp);
  }
  __syncthreads();
  int is_logits = (blk < nb_log);
  const unsigned short* Bm; const float* bias; float* out; int n0, ldo;
  if (is_logits){ Bm = WoutT; bias = bout; out = logits; n0 = blk * 64; ldo = VV; }
  else { Bm = W1T; bias = b1; out = w1h; n0 = (blk - nb_log) * 64; ldo = 512; }
  int lane = tid & 63, w = tid >> 6;
  int l15 = lane & 15, quad = lane >> 4;
  int mt = (w & 1) * 16;
  int nbase = n0 + (w >> 1) * 32;
  f32x4 acc[2];
  acc[0] = (f32x4)0.0f; acc[1] = (f32x4)0.0f;
  const unsigned short* arow = hs + (mt + l15) * 520 + quad * 8;
  #pragma unroll 2
  for (int k0 = 0; k0 < 512; k0 += 32){
    bf16x8 a = *(const bf16x8*)(arow + k0);
    #pragma unroll
    for (int s = 0; s < 2; s++){
      const unsigned short* br = Bm + (size_t)(nbase + s * 16 + l15) * 512 + k0 + quad * 8;
      acc[s] = __builtin_amdgcn_mfma_f32_16x16x32_bf16(a, *(const bf16x8*)br, acc[s], 0, 0, 0);
    }
  }
  float vv[2][4];
  #pragma unroll
  for (int s = 0; s < 2; s++){
    int col = nbase + s * 16 + l15;
    float bi = bias[col];
    #pragma unroll
    for (int r = 0; r < 4; r++){
      int row = mt + quad * 4 + r;
      vv[s][r] = acc[s][r] + bi;
      out[(size_t)row * ldo + col] = vv[s][r];
    }
  }
  if (is_logits){
    #pragma unroll
    for (int r = 0; r < 4; r++){
      float m = fmaxf(vv[0][r], vv[1][r]);
      m = fmaxf(m, __shfl_xor(m, 1)); m = fmaxf(m, __shfl_xor(m, 2));
      m = fmaxf(m, __shfl_xor(m, 4)); m = fmaxf(m, __shfl_xor(m, 8));
      float e = __expf(vv[0][r] - m) + __expf(vv[1][r] - m);
      e += __shfl_xor(e, 1); e += __shfl_xor(e, 2); e += __shfl_xor(e, 4); e += __shfl_xor(e, 8);
      if (l15 == 0){ smp[w][quad * 4 + r][0] = m; smp[w][quad * 4 + r][1] = e; }
    }
    __syncthreads();
    if (tid < 32){
      int half = tid >> 4, row = tid & 15;
      float ma = smp[half][row][0], mb = smp[half + 2][row][0];
      float M = fmaxf(ma, mb);
      float S = smp[half][row][1] * __expf(ma - M) + smp[half + 2][row][1] * __expf(mb - M);
      tilems[((size_t)blk * 32 + half * 16 + row) * 2] = M;
      tilems[((size_t)blk * 32 + half * 16 + row) * 2 + 1] = S;
    }
  }
}

__global__ __launch_bounds__(256) void k_score(
    const unsigned short* __restrict__ ef_bf, const float* __restrict__ w1h,
    const float* __restrict__ Wc, const float* __restrict__ Va, const float* __restrict__ bv,
    const float* __restrict__ cov, float* __restrict__ scores,
    const float* __restrict__ h_new, const float* __restrict__ Wp,
    float* __restrict__ pgen_hd)
{
  int blk = blockIdx.x;
  int tid = threadIdx.x;
  if (blk < 800){
    __shared__ float whs[512], wcs[512], vas[512];
    int b = blk / 25, lt = blk - b * 25;
    for (int i = tid; i < 512; i += 256){ whs[i] = w1h[b * 512 + i]; wcs[i] = Wc[i]; vas[i] = Va[i]; }
    __syncthreads();
    int li = tid >> 4;
    int a0 = (tid & 15) * 32;
    int l = lt * 16 + li;
    float covl = cov ? cov[b * 400 + l] : 0.f;
    const unsigned short* ef = ef_bf + (size_t)(b * 400 + l) * 512 + a0;
    float p = 0.f;
    #pragma unroll
    for (int i = 0; i < 32; i += 8){
      bf16x8 v8 = *(const bf16x8*)(ef + i);
      #pragma unroll
      for (int j = 0; j < 8; j++){
        int aa = a0 + i + j;
        float arg = whs[aa] + bf2f((unsigned short)v8[j]) + covl * wcs[aa];
        p += fast_tanh(arg) * vas[aa];
      }
    }
    p += __shfl_xor(p, 1); p += __shfl_xor(p, 2); p += __shfl_xor(p, 4); p += __shfl_xor(p, 8);
    if ((tid & 15) == 0) scores[b * 400 + l] = p + bv[0];
    return;
  }
  blk -= 800;
  {
    int b = blk;
    __shared__ float red[256];
    float p = 0.f;
    for (int i = tid; i < 512; i += 256) p += h_new[b * 512 + i] * Wp[512 + i];
    red[tid] = p; __syncthreads();
    for (int s = 128; s > 0; s >>= 1){ if (tid < s) red[tid] += red[tid + s]; __syncthreads(); }
    if (tid == 0) pgen_hd[b] = red[0];
  }
}

__global__ __launch_bounds__(256) void k_attn_ctx(
    const float* __restrict__ scores, const float* __restrict__ mask,
    const float* __restrict__ cov_in, float* attn_out, float* cov_out,
    const unsigned short* __restrict__ enc_bf,
    float* __restrict__ ctx_out, float* ctxf_out, const float* __restrict__ Wp,
    float* __restrict__ pgen_cn, float* __restrict__ pgen_co,
    const float* __restrict__ tilems, float* __restrict__ rowMS)
{
  int b = blockIdx.x >> 3, ct = blockIdx.x & 7;
  int tid = threadIdx.x;
  __shared__ float at[400];
  __shared__ float red[512];
  float mx = -1e30f;
  for (int i = tid; i < 400; i += 256){ float s = scores[b * 400 + i]; at[i] = s; mx = fmaxf(mx, s); }
  red[tid] = mx; __syncthreads();
  for (int s = 128; s > 0; s >>= 1){ if (tid < s) red[tid] = fmaxf(red[tid], red[tid + s]); __syncthreads(); }
  mx = red[0]; __syncthreads();
  float sm = 0.f;
  for (int i = tid; i < 400; i += 256){ float e = __expf(at[i] - mx) * mask[b * 400 + i]; at[i] = e; sm += e; }
  red[tid] = sm; __syncthreads();
  for (int s = 128; s > 0; s >>= 1){ if (tid < s) red[tid] += red[tid + s]; __syncthreads(); }
  float inv = __builtin_amdgcn_rcpf(red[0]);
  __syncthreads();
  for (int i = tid; i < 400; i += 256){
    float a = at[i] * inv; at[i] = a;
    if (ct == 0){
      if (attn_out) attn_out[b * 400 + i] = a;
      float cv = (cov_in ? cov_in[b * 400 + i] : 0.f) + a;
      if (cov_out) cov_out[b * 400 + i] = cv;
    }
  }
  __syncthreads();
  int colp = (tid & 31) * 2;
  int chunk = tid >> 5;
  const unsigned short* base = enc_bf + (size_t)b * 400 * 512 + ct * 64 + colp;
  float a0 = 0.f, a1 = 0.f;
  for (int i = 0; i < 50; i++){
    int l = chunk * 50 + i;
    unsigned int u = *(const unsigned int*)(base + (size_t)l * 512);
    float av = at[l];
    a0 += av * bf2f((unsigned short)(u & 0xffffu));
    a1 += av * bf2f((unsigned short)(u >> 16));
  }
  red[chunk * 64 + colp] = a0; red[chunk * 64 + colp + 1] = a1;
  __syncthreads();
  if (tid < 64){
    float s = 0.f;
    #pragma unroll
    for (int c = 0; c < 8; c++) s += red[c * 64 + tid];
    int col = ct * 64 + tid;
    ctx_out[b * 512 + col] = s;
    if (ctxf_out) ctxf_out[b * 512 + col] = s;
    float cn = s * Wp[col];
    float co = s * Wp[1280 + col];
    #pragma unroll
    for (int off = 32; off > 0; off >>= 1){ cn += __shfl_down(cn, off); co += __shfl_down(co, off); }
    if (tid == 0){ pgen_cn[b * 8 + ct] = cn; pgen_co[b * 8 + ct] = co; }
  }
  __syncthreads();
  if (ct == 0 && tilems != nullptr){
    float M = -1e30f;
    for (int i = tid; i < 500; i += 256) M = fmaxf(M, tilems[(i * 32 + b) * 2]);
    red[tid] = M; __syncthreads();
    for (int s = 128; s > 0; s >>= 1){ if (tid < s) red[tid] = fmaxf(red[tid], red[tid + s]); __syncthreads(); }
    M = red[0]; __syncthreads();
    float S = 0.f;
    for (int i = tid; i < 500; i += 256) S += tilems[(i * 32 + b) * 2 + 1] * __expf(tilems[(i * 32 + b) * 2] - M);
    red[tid] = S; __syncthreads();
    for (int s = 128; s > 0; s >>= 1){ if (tid < s) red[tid] += red[tid + s]; __syncthreads(); }
    if (tid == 0){ rowMS[b * 2] = M; rowMS[b * 2 + 1] = red[0]; }
  }
}

// ================= persistent mega-kernel (decode loop, REGULAR launch) =================
struct MP {
  const float* mask; const int* eidx;
  const float* Wc; const float* Va; const float* bv;
  const float* b1; const float* bout; const float* Wp; const float* bp;
  const unsigned short* WgT; const unsigned short* UgT;
  const unsigned short* W1T; const unsigned short* WoutT;
  const unsigned short* ef_bf; const unsigned short* enc_bf;
  const float* embW;
  float* logits; float* tilems; float* w1h; float* scores; float* rowMS;
  float* pgen_hd; float* pgen_cn; float* pgen_co0; float* pgen_co1;
  float* pgen_emb;
  float* hbuf0; float* hbuf1; float* ctxbuf0; float* ctxbuf1;
  unsigned short* h_bf;
  float* final_; float* attns; float* covs; float* hf; float* ctxf; float* pgens;
  unsigned* bar;
};

// fence-hardened sense-reversing grid barrier (agent scope + device fences for
// cross-XCD L2 visibility; all 512 blocks co-resident by capacity)
__device__ __forceinline__ void gbar(unsigned* bar)
{
  __syncthreads();
  __threadfence();   // publish this thread's writes device-wide (L2 wb across XCDs)
  if (threadIdx.x == 0){
    unsigned g = __hip_atomic_load(&bar[1], __ATOMIC_ACQUIRE, __HIP_MEMORY_SCOPE_AGENT);
    unsigned v = __hip_atomic_fetch_add(&bar[0], 1u, __ATOMIC_ACQ_REL, __HIP_MEMORY_SCOPE_AGENT);
    if (v == (unsigned)(NBLK - 1)){
      __hip_atomic_store(&bar[0], 0u, __ATOMIC_RELAXED, __HIP_MEMORY_SCOPE_AGENT);
      __hip_atomic_store(&bar[1], g + 1u, __ATOMIC_RELEASE, __HIP_MEMORY_SCOPE_AGENT);
    } else {
      while (__hip_atomic_load(&bar[1], __ATOMIC_ACQUIRE, __HIP_MEMORY_SCOPE_AGENT) == g)
        __builtin_amdgcn_s_sleep(8);
    }
  }
  __syncthreads();
  __threadfence();   // invalidate stale cache lines before reading others' data
}

// ---------------- final-dist writer (leading sync guards s_pg reuse) ----------------
__device__ void final_dist_write(int f, int tid, const MP& P,
    const float* __restrict__ pgen_co, const float* __restrict__ pgen_emb_t,
    float* __restrict__ final_t, float* __restrict__ pgens_t)
{
  __shared__ float s_pg;
  __syncthreads();
  int b = f >> 4, vt = f & 15;
  if (tid == 0){
    float p = P.pgen_hd[b] + pgen_emb_t[b] + P.bp[0];
    #pragma unroll
    for (int j = 0; j < 8; j++) p += P.pgen_cn[b * 8 + j] + pgen_co[b * 8 + j];
    float pg = fast_sigmoid(p);
    s_pg = pg;
    if (vt == 0) pgens_t[b] = pg;
  }
  __syncthreads();
  float pg = s_pg;
  float M = P.rowMS[b * 2];
  float Sinv = __builtin_amdgcn_rcpf(P.rowMS[b * 2 + 1]);
  const float* lg = P.logits + (size_t)b * VV;
  float* dst = final_t + (size_t)b * VEXT;
  int v0 = vt * 2048 + tid * 8;
  if (v0 + 7 < VV){
    f32x4 x0 = *(const f32x4*)(lg + v0);
    f32x4 x1 = *(const f32x4*)(lg + v0 + 4);
    f32x2 y;
    y.x = pg * __expf(x0.x - M) * Sinv; y.y = pg * __expf(x0.y - M) * Sinv;
    __builtin_nontemporal_store(y, (f32x2*)(dst + v0));
    y.x = pg * __expf(x0.z - M) * Sinv; y.y = pg * __expf(x0.w - M) * Sinv;
    __builtin_nontemporal_store(y, (f32x2*)(dst + v0 + 2));
    y.x = pg * __expf(x1.x - M) * Sinv; y.y = pg * __expf(x1.y - M) * Sinv;
    __builtin_nontemporal_store(y, (f32x2*)(dst + v0 + 4));
    y.x = pg * __expf(x1.z - M) * Sinv; y.y = pg * __expf(x1.w - M) * Sinv;
    __builtin_nontemporal_store(y, (f32x2*)(dst + v0 + 6));
  } else {
    #pragma unroll
    for (int j = 0; j < 8; j++){
      int v = v0 + j;
      float val = (v < VV) ? pg * __expf(lg[v] - M) * Sinv : 0.f;
      if (v < VEXT) __builtin_nontemporal_store(val, dst + v);
    }
  }
}

// ---------------- GRU step (blocks 0..7) ----------------
__device__ __forceinline__ void dev_gru(int blk, int tid, const MP& P,
    const float* __restrict__ ctx_old, const float* __restrict__ h_old,
    const float* __restrict__ embW_t,
    float* __restrict__ h_new, float* hf_out, unsigned short* xs)
{
  for (int i = tid; i < 32 * 512; i += 256){
    int bb = i >> 9, c = i & 511;
    xs[bb * 520 + c] = f2bf(ctx_old[i]);
  }
  __syncthreads();
  int lane = tid & 63, w = tid >> 6;
  int l15 = lane & 15, quad = lane >> 4;
  int mt = (w & 1) * 16;
  int n0 = blk * 64 + (w >> 1) * 32;
  f32x4 accZ[2], accR[2], accH[2], accU[2];
  #pragma unroll
  for (int s = 0; s < 2; s++){
    int col = n0 + s * 16 + l15;
    #pragma unroll
    for (int r = 0; r < 4; r++){
      int row = mt + quad * 4 + r;
      const float* e = embW_t + (size_t)row * 1536 + col;
      accZ[s][r] = e[0]; accR[s][r] = e[512]; accH[s][r] = e[1024];
      accU[s][r] = 0.f;
    }
  }
  for (int k0 = 0; k0 < 512; k0 += 32){
    bf16x8 a = *(const bf16x8*)(xs + (mt + l15) * 520 + k0 + quad * 8);
    #pragma unroll
    for (int s = 0; s < 2; s++){
      int col = n0 + s * 16 + l15;
      const unsigned short* bz = P.WgT + (size_t)col * 768 + 256 + k0 + quad * 8;
      const unsigned short* br = P.WgT + (size_t)(col + 512) * 768 + 256 + k0 + quad * 8;
      const unsigned short* bh = P.WgT + (size_t)(col + 1024) * 768 + 256 + k0 + quad * 8;
      accZ[s] = __builtin_amdgcn_mfma_f32_16x16x32_bf16(a, *(const bf16x8*)bz, accZ[s], 0, 0, 0);
      accR[s] = __builtin_amdgcn_mfma_f32_16x16x32_bf16(a, *(const bf16x8*)br, accR[s], 0, 0, 0);
      accH[s] = __builtin_amdgcn_mfma_f32_16x16x32_bf16(a, *(const bf16x8*)bh, accH[s], 0, 0, 0);
    }
  }
  __syncthreads();
  for (int i = tid; i < 32 * 512; i += 256){
    int bb = i >> 9, c = i & 511;
    xs[bb * 520 + c] = f2bf(h_old[i]);
  }
  __syncthreads();
  for (int k0 = 0; k0 < 512; k0 += 32){
    bf16x8 a = *(const bf16x8*)(xs + (mt + l15) * 520 + k0 + quad * 8);
    #pragma unroll
    for (int s = 0; s < 2; s++){
      int col = n0 + s * 16 + l15;
      const unsigned short* bz = P.UgT + (size_t)col * 512 + k0 + quad * 8;
      const unsigned short* br = P.UgT + (size_t)(col + 512) * 512 + k0 + quad * 8;
      const unsigned short* bh = P.UgT + (size_t)(col + 1024) * 512 + k0 + quad * 8;
      accZ[s] = __builtin_amdgcn_mfma_f32_16x16x32_bf16(a, *(const bf16x8*)bz, accZ[s], 0, 0, 0);
      accR[s] = __builtin_amdgcn_mfma_f32_16x16x32_bf16(a, *(const bf16x8*)br, accR[s], 0, 0, 0);
      accU[s] = __builtin_amdgcn_mfma_f32_16x16x32_bf16(a, *(const bf16x8*)bh, accU[s], 0, 0, 0);
    }
  }
  #pragma unroll
  for (int s = 0; s < 2; s++){
    int col = n0 + s * 16 + l15;
    #pragma unroll
    for (int r = 0; r < 4; r++){
      int bb = mt + quad * 4 + r;
      float z  = fast_sigmoid(accZ[s][r]);
      float rr = fast_sigmoid(accR[s][r]);
      float hh = fast_tanh(accH[s][r] + rr * accU[s][r]);
      float ho = h_old[bb * 512 + col];
      float hn = z * ho + (1.f - z) * hh;
      h_new[bb * 512 + col] = hn;
      P.h_bf[bb * 512 + col] = f2bf(hn);
      if (hf_out) hf_out[bb * 512 + col] = hn;
    }
  }
}

// ---- logits tile (u<500) or w1h tile (500<=u<508) ----
__device__ __forceinline__ void dev_gemm(int u, int tid, const MP& P,
                                         unsigned short* hs, float* smp)
{
  for (int i = tid; i < 8192; i += 256){
    int bb = i >> 8;
    int cp = (i & 255) * 2;
    *(unsigned int*)(hs + bb * 520 + cp) = *(const unsigned int*)(P.h_bf + bb * 512 + cp);
  }
  __syncthreads();
  int is_logits = (u < 500);
  const unsigned short* Bm; const float* bias; float* out; int n0, ldo;
  if (is_logits){ Bm = P.WoutT; bias = P.bout; out = P.logits; n0 = u * 64; ldo = VV; }
  else { Bm = P.W1T; bias = P.b1; out = P.w1h; n0 = (u - 500) * 64; ldo = 512; }
  int lane = tid & 63, w = tid >> 6;
  int l15 = lane & 15, quad = lane >> 4;
  int mt = (w & 1) * 16;
  int nbase = n0 + (w >> 1) * 32;
  f32x4 acc[2];
  acc[0] = (f32x4)0.0f; acc[1] = (f32x4)0.0f;
  const unsigned short* arow = hs + (mt + l15) * 520 + quad * 8;
  #pragma unroll 2
  for (int k0 = 0; k0 < 512; k0 += 32){
    bf16x8 a = *(const bf16x8*)(arow + k0);
    #pragma unroll
    for (int s = 0; s < 2; s++){
      const unsigned short* br = Bm + (size_t)(nbase + s * 16 + l15) * 512 + k0 + quad * 8;
      acc[s] = __builtin_amdgcn_mfma_f32_16x16x32_bf16(a, *(const bf16x8*)br, acc[s], 0, 0, 0);
    }
  }
  float vv[2][4];
  #pragma unroll
  for (int s = 0; s < 2; s++){
    int col = nbase + s * 16 + l15;
    float bi = bias[col];
    #pragma unroll
    for (int r = 0; r < 4; r++){
      int row = mt + quad * 4 + r;
      vv[s][r] = acc[s][r] + bi;
      out[(size_t)row * ldo + col] = vv[s][r];
    }
  }
  if (is_logits){
    #pragma unroll
    for (int r = 0; r < 4; r++){
      float m = fmaxf(vv[0][r], vv[1][r]);
      m = fmaxf(m, __shfl_xor(m, 1)); m = fmaxf(m, __shfl_xor(m, 2));
      m = fmaxf(m, __shfl_xor(m, 4)); m = fmaxf(m, __shfl_xor(m, 8));
      float e = __expf(vv[0][r] - m) + __expf(vv[1][r] - m);
      e += __shfl_xor(e, 1); e += __shfl_xor(e, 2); e += __shfl_xor(e, 4); e += __shfl_xor(e, 8);
      if (l15 == 0){ smp[(w * 16 + quad * 4 + r) * 2] = m; smp[(w * 16 + quad * 4 + r) * 2 + 1] = e; }
    }
    __syncthreads();
    if (tid < 32){
      int half = tid >> 4, row = tid & 15;
      float ma = smp[(half * 16 + row) * 2],     mb = smp[((half + 2) * 16 + row) * 2];
      float M = fmaxf(ma, mb);
      float S = smp[(half * 16 + row) * 2 + 1] * __expf(ma - M)
              + smp[((half + 2) * 16 + row) * 2 + 1] * __expf(mb - M);
      P.tilems[((size_t)u * 32 + half * 16 + row) * 2] = M;
      P.tilems[((size_t)u * 32 + half * 16 + row) * 2 + 1] = S;
    }
  }
}

__device__ __forceinline__ void dev_scatter(int c, int tid, const MP& P,
    const float* __restrict__ attn_prev, const float* __restrict__ pgens_prev,
    float* __restrict__ final_prev)
{
  int i = c * 256 + tid;
  if (i >= 12800) return;
  int b = i / 400;
  float wv = (1.f - pgens_prev[b]) * attn_prev[i];
  atomicAdd(final_prev + (size_t)b * VEXT + P.eidx[i], wv);
}

__device__ __forceinline__ void dev_score(int u, int tid, const MP& P,
                                          const float* cov, float* sf)
{
  __syncthreads();
  float* whs = sf; float* wcs = sf + 512; float* vas = sf + 1024;
  int b = u / 25, lt = u - b * 25;
  for (int i = tid; i < 512; i += 256){ whs[i] = P.w1h[b * 512 + i]; wcs[i] = P.Wc[i]; vas[i] = P.Va[i]; }
  __syncthreads();
  int li = tid >> 4;
  int a0 = (tid & 15) * 32;
  int l = lt * 16 + li;
  float covl = cov ? cov[b * 400 + l] : 0.f;
  const unsigned short* ef = P.ef_bf + (size_t)(b * 400 + l) * 512 + a0;
  float pv = 0.f;
  #pragma unroll
  for (int i = 0; i < 32; i += 8){
    bf16x8 v8 = *(const bf16x8*)(ef + i);
    #pragma unroll
    for (int j = 0; j < 8; j++){
      int aa = a0 + i + j;
      float arg = whs[aa] + bf2f((unsigned short)v8[j]) + covl * wcs[aa];
      pv += fast_tanh(arg) * vas[aa];
    }
  }
  pv += __shfl_xor(pv, 1); pv += __shfl_xor(pv, 2); pv += __shfl_xor(pv, 4); pv += __shfl_xor(pv, 8);
  if ((tid & 15) == 0) P.scores[b * 400 + l] = pv + P.bv[0];
}

__device__ __forceinline__ void dev_pgen_hd(int b, int tid, const MP& P,
                                            const float* __restrict__ h, float* red)
{
  __syncthreads();
  float pv = 0.f;
  for (int i = tid; i < 512; i += 256) pv += h[b * 512 + i] * P.Wp[512 + i];
  red[tid] = pv; __syncthreads();
  for (int s = 128; s > 0; s >>= 1){ if (tid < s) red[tid] += red[tid + s]; __syncthreads(); }
  if (tid == 0) P.pgen_hd[b] = red[0];
}

__device__ __forceinline__ void dev_attn(int blk, int tid, const MP& P,
    const float* cov_in, float* attn_out, float* cov_out,
    float* __restrict__ ctx_out, float* ctxf_out, float* __restrict__ pgen_co_out,
    bool do_rowms, float* sf)
{
  __syncthreads();
  int b = blk >> 3, ct = blk & 7;
  float* at  = sf;            // [400]
  float* red = sf + 512;      // [512]
  float mx = -1e30f;
  for (int i = tid; i < 400; i += 256){ float s = P.scores[b * 400 + i]; at[i] = s; mx = fmaxf(mx, s); }
  red[tid] = mx; __syncthreads();
  for (int s = 128; s > 0; s >>= 1){ if (tid < s) red[tid] = fmaxf(red[tid], red[tid + s]); __syncthreads(); }
  mx = red[0]; __syncthreads();
  float sm = 0.f;
  for (int i = tid; i < 400; i += 256){ float e = __expf(at[i] - mx) * P.mask[b * 400 + i]; at[i] = e; sm += e; }
  red[tid] = sm; __syncthreads();
  for (int s = 128; s > 0; s >>= 1){ if (tid < s) red[tid] += red[tid + s]; __syncthreads(); }
  float inv = __builtin_amdgcn_rcpf(red[0]);
  __syncthreads();
  for (int i = tid; i < 400; i += 256){
    float a = at[i] * inv; at[i] = a;
    if (ct == 0){
      if (attn_out) attn_out[b * 400 + i] = a;
      float cv = (cov_in ? cov_in[b * 400 + i] : 0.f) + a;
      if (cov_out) cov_out[b * 400 + i] = cv;
    }
  }
  __syncthreads();
  int colp = (tid & 31) * 2;
  int chunk = tid >> 5;
  const unsigned short* base = P.enc_bf + (size_t)b * 400 * 512 + ct * 64 + colp;
  float a0 = 0.f, a1 = 0.f;
  for (int i = 0; i < 50; i++){
    int l = chunk * 50 + i;
    unsigned int uu = *(const unsigned int*)(base + (size_t)l * 512);
    float av = at[l];
    a0 += av * bf2f((unsigned short)(uu & 0xffffu));
    a1 += av * bf2f((unsigned short)(uu >> 16));
  }
  red[chunk * 64 + colp] = a0; red[chunk * 64 + colp + 1] = a1;
  __syncthreads();
  if (tid < 64){
    float s = 0.f;
    #pragma unroll
    for (int c = 0; c < 8; c++) s += red[c * 64 + tid];
    int col = ct * 64 + tid;
    ctx_out[b * 512 + col] = s;
    if (ctxf_out) ctxf_out[b * 512 + col] = s;
    float cn = s * P.Wp[col];
    float co = s * P.Wp[1280 + col];
    #pragma unroll
    for (int off = 32; off > 0; off >>= 1){ cn += __shfl_down(cn, off); co += __shfl_down(co, off); }
    if (tid == 0){ P.pgen_cn[b * 8 + ct] = cn; pgen_co_out[b * 8 + ct] = co; }
  }
  __syncthreads();
  if (do_rowms && ct == 0){
    float M = -1e30f;
    for (int i = tid; i < 500; i += 256) M = fmaxf(M, P.tilems[(i * 32 + b) * 2]);
    red[tid] = M; __syncthreads();
    for (int s = 128; s > 0; s >>= 1){ if (tid < s) red[tid] = fmaxf(red[tid], red[tid + s]); __syncthreads(); }
    M = red[0]; __syncthreads();
    float S = 0.f;
    for (int i = tid; i < 500; i += 256)
      S += P.tilems[(i * 32 + b) * 2 + 1] * __expf(P.tilems[(i * 32 + b) * 2] - M);
    red[tid] = S; __syncthreads();
    for (int s = 128; s > 0; s >>= 1){ if (tid < s) red[tid] += red[tid + s]; __syncthreads(); }
    if (tid == 0){ P.rowMS[b * 2] = M; P.rowMS[b * 2 + 1] = red[0]; }
  }
}

__global__ __launch_bounds__(256, 2) void k_mega(MP P)
{
  __shared__ unsigned short s_u16[32 * 520];
  __shared__ float s_f[1552];
  __shared__ float s_smp[4 * 16 * 2];
  int blk = blockIdx.x, tid = threadIdx.x;

  // decode loop; initial state (attns[0], covs[0], ctx0, w1h(h0), scores(h0),
  // pgen_hd(h0), pgen_co1) comes from the standalone round-0 pre kernels.
  for (int t = 0; t < 40; t++){
    const int p = t & 1;
    float* h_old  = p ? P.hbuf1 : P.hbuf0;
    float* h_new  = p ? P.hbuf0 : P.hbuf1;
    float* c_old  = p ? P.ctxbuf1 : P.ctxbuf0;
    float* c_new  = p ? P.ctxbuf0 : P.ctxbuf1;
    float* co_cur = p ? P.pgen_co1 : P.pgen_co0;

    // ---- phase A: GRU(t) + final(t-1) ----
    if (blk < 8){
      dev_gru(blk, tid, P, c_old, h_old, P.embW + (size_t)t * 32 * 1536,
              h_new, (t == 39) ? P.hf : nullptr, s_u16);
    } else if (t >= 1){
      for (int f = blk - 8; f < 512; f += 504)
        final_dist_write(f, tid, P, co_cur, P.pgen_emb + (t - 1) * 32,
                         P.final_ + (size_t)(t - 1) * 32 * VEXT, P.pgens + (t - 1) * 32);
    }
    gbar(P.bar);

    // ---- phase B: logits(t) + w1h(t) + scatter(t-1) ----
    if (blk < 508) dev_gemm(blk, tid, P, s_u16, s_smp);
    if (t >= 1){
      const float* attn_prev  = P.attns + (size_t)(t - 1) * 12800;
      const float* pgens_prev = P.pgens + (t - 1) * 32;
      float* final_prev = P.final_ + (size_t)(t - 1) * 32 * VEXT;
      if (blk >= 508) dev_scatter(blk - 508, tid, P, attn_prev, pgens_prev, final_prev);
      if (blk < 46)   dev_scatter(blk + 4,   tid, P, attn_prev, pgens_prev, final_prev);
    }
    gbar(P.bar);

    // ---- phase C: scores(t) + pgen_hd(t) ----
    {
      const float* cov_t = P.covs + (size_t)t * 12800;
      dev_score(blk, tid, P, cov_t, s_f);
      if (blk < 320){
        int u2 = blk + 512;
        if (u2 < 800) dev_score(u2, tid, P, cov_t, s_f);
        else dev_pgen_hd(u2 - 800, tid, P, h_new, s_f);
      }
    }
    gbar(P.bar);

    // ---- phase D: attn(t) softmax + context + pgen dots + rowMS ----
    if (blk < 256)
      dev_attn(blk, tid, P, P.covs + (size_t)t * 12800,
               (t < 39) ? P.attns + (size_t)(t + 1) * 12800 : nullptr,
               (t < 39) ? P.covs + (size_t)(t + 1) * 12800 : nullptr,
               c_new, (t == 39) ? P.ctxf : nullptr, co_cur, true, s_f);
    gbar(P.bar);
  }

  // ---- epilogue: final(39) + scatter(39) ----
  final_dist_write(blk, tid, P, P.pgen_co0, P.pgen_emb + 39 * 32,
                   P.final_ + (size_t)39 * 32 * VEXT, P.pgens + 39 * 32);
  gbar(P.bar);
  if (blk < 50) dev_scatter(blk, tid, P, P.attns + (size_t)39 * 12800,
                            P.pgens + 39 * 32, P.final_ + (size_t)39 * 32 * VEXT);
}

extern "C" void kernel_launch(void* const* d_in, const int* in_sizes, int n_in,
                              void* d_out, int out_size, void* d_ws, size_t ws_size,
                              hipStream_t stream) {
  const int*   dec_inp    = (const int*)d_in[0];
  const int*   eidx       = (const int*)d_in[1];
  const float* mask       = (const float*)d_in[2];
  const float* enc        = (const float*)d_in[4];
  const float* dec_hidden = (const float*)d_in[5];
  const float* embedding  = (const float*)d_in[6];
  const float* W1  = (const float*)d_in[7];
  const float* b1  = (const float*)d_in[8];
  const float* W2  = (const float*)d_in[9];
  const float* b2  = (const float*)d_in[10];
  const float* Wc  = (const float*)d_in[11];
  const float* Va  = (const float*)d_in[12];
  const float* bv  = (const float*)d_in[13];
  const float* Wg  = (const float*)d_in[14];
  const float* Ug  = (const float*)d_in[15];
  const float* bg  = (const float*)d_in[16];
  const float* Wout = (const float*)d_in[17];
  const float* bout = (const float*)d_in[18];
  const float* Wp  = (const float*)d_in[19];
  const float* bp  = (const float*)d_in[20];

  float* out    = (float*)d_out;
  float* final_ = out;                               // 40*32*32050
  float* attns  = out + (size_t)40 * 32 * VEXT;      // 40*32*400
  float* covs   = attns + 512000;
  float* hf     = covs + 512000;
  float* ctxf   = hf + 16384;
  float* pgens  = ctxf + 16384;

  char* wsb = (char*)d_ws; size_t off = 0;
  auto A = [&](size_t bytes)->char*{ char* p = wsb + off; off += (bytes + 255) & ~(size_t)255; return p; };
  float* logits   = (float*)A((size_t)32 * VV * 4);
  float* embW     = (float*)A((size_t)40 * 32 * 1536 * 4);
  float* tilems   = (float*)A(500 * 32 * 2 * 4);
  float* hbuf0    = (float*)A(65536);
  float* hbuf1    = (float*)A(65536);
  float* ctxbuf0  = (float*)A(65536);
  float* ctxbuf1  = (float*)A(65536);
  float* w1h      = (float*)A(65536);
  float* scores   = (float*)A(51200);
  float* rowMS    = (float*)A(256);
  float* pgen_hd  = (float*)A(128);
  float* pgen_cn  = (float*)A(1024);
  float* pgen_co0 = (float*)A(1024);
  float* pgen_co1 = (float*)A(1024);
  float* pgen_emb = (float*)A(40 * 32 * 4);
  unsigned* barm  = (unsigned*)A(256);
  unsigned short* h_bf   = (unsigned short*)A(32768);
  unsigned short* enc_bf = (unsigned short*)A((size_t)32 * 400 * 512 * 2);
  unsigned short* ef_bf  = (unsigned short*)A((size_t)32 * 400 * 512 * 2);
  unsigned short* W2T    = (unsigned short*)A(524288);
  unsigned short* W1T    = (unsigned short*)A(524288);
  unsigned short* WgT    = (unsigned short*)A(2359296);
  unsigned short* UgT    = (unsigned short*)A(1572864);
  unsigned short* WoutT  = (unsigned short*)A((size_t)VV * 512 * 2);

  // ---- prologue (parallel-wide prep; zeroes barrier state) ----
  k_prep<<<7856, 256, 0, stream>>>(Wout, Wg, Ug, W1, W2, enc, dec_hidden, dec_inp, embedding, Wp,
                                   WoutT, WgT, UgT, W1T, W2T, enc_bf, hbuf0, h_bf, pgen_emb, barm);
  k_embw<<<480, 256, 0, stream>>>(dec_inp, embedding, WgT, bg, embW);
  k_encfeat<<<1600, 256, 0, stream>>>(enc_bf, W2T, b2, ef_bf);

  // ---- round-0 pre-decode kernels (bit-identical initial state) ----
  k_gemm_h<<<8, 256, 0, stream>>>(h_bf, WoutT, bout, logits, W1T, b1, w1h, 0, tilems,
                                  eidx, nullptr, nullptr, nullptr); // w1h(h0) only
  k_score<<<832, 256, 0, stream>>>(ef_bf, w1h, Wc, Va, bv, nullptr, scores,
                                   hbuf0, Wp, pgen_hd);
  k_attn_ctx<<<256, 256, 0, stream>>>(scores, mask, nullptr, attns, covs, enc_bf,
                                      ctxbuf0, nullptr, Wp, pgen_cn, pgen_co1,
                                      nullptr, rowMS);

  // ---- persistent decode loop: REGULAR launch (graph-capturable), 2 blocks/CU ----
  MP mp;
  mp.mask = mask; mp.eidx = eidx;
  mp.Wc = Wc; mp.Va = Va; mp.bv = bv;
  mp.b1 = b1; mp.bout = bout; mp.Wp = Wp; mp.bp = bp;
  mp.WgT = WgT; mp.UgT = UgT; mp.W1T = W1T; mp.WoutT = WoutT;
  mp.ef_bf = ef_bf; mp.enc_bf = enc_bf;
  mp.embW = embW;
  mp.logits = logits; mp.tilems = tilems; mp.w1h = w1h; mp.scores = scores; mp.rowMS = rowMS;
  mp.pgen_hd = pgen_hd; mp.pgen_cn = pgen_cn; mp.pgen_co0 = pgen_co0; mp.pgen_co1 = pgen_co1;
  mp.pgen_emb = pgen_emb;
  mp.hbuf0 = hbuf0; mp.hbuf1 = hbuf1; mp.ctxbuf0 = ctxbuf0; mp.ctxbuf1 = ctxbuf1;
  mp.h_bf = h_bf;
  mp.final_ = final_; mp.attns = attns; mp.covs = covs; mp.hf = hf; mp.ctxf = ctxf; mp.pgens = pgens;
  mp.bar = barm;
  k_mega<<<dim3(NBLK), dim3(256), 0, stream>>>(mp);
}

// Round 9
// 8950.838 us; speedup vs baseline: 4.2482x; 4.2482x over previous
//
#include <hip/hip_runtime.h>

// PGN decoder: B=32, L=400, T=40 steps, H=A=512, E=256, V=32000, oov=50.
// Outputs (flat in d_out, fp32): final (40,32,32050) | attns (40,32,400) |
// covs (40,32,400) | h_f (32,512) | ctx_f (32,512) | pgens (40,32)
//
// Structure: prologue + round-0 pre-decode dispatches, then ONE persistent kernel
// (regular launch, 512 blocks = 2/CU co-resident by capacity) running the 40-step
// decode loop. All cross-phase data moves via agent-scope relaxed atomics (sc1,
// coherence-point accesses) so the grid barrier needs NO cache maintenance:
// monotonic counter + relaxed RMW/poll. (r8's 220us/barrier was the per-thread
// __threadfence L2-writeback/invalidate storm.)
#define BB 32
#define LL 400
#define TT 40
#define HH 512
#define VV 32000
#define VEXT 32050
#define NBLK 512

typedef __attribute__((ext_vector_type(8))) short bf16x8;
typedef __attribute__((ext_vector_type(4))) float f32x4;
typedef __attribute__((ext_vector_type(2))) float f32x2;

__device__ __forceinline__ float bf2f(unsigned short u){
  union { unsigned int i; float f; } v; v.i = ((unsigned int)u) << 16; return v.f;
}
__device__ __forceinline__ unsigned short f2bf(float f){
  union { float f; unsigned int i; } v; v.f = f;
  unsigned int i = v.i;
  return (unsigned short)((i + 0x7FFFu + ((i >> 16) & 1u)) >> 16); // RNE
}
__device__ __forceinline__ float fast_tanh(float x){
  x = fminf(20.f, fmaxf(-20.f, x));
  float e = __expf(2.f * x);
  return (e - 1.f) * __builtin_amdgcn_rcpf(e + 1.f);
}
__device__ __forceinline__ float fast_sigmoid(float x){
  x = fminf(30.f, fmaxf(-30.f, x));
  return __builtin_amdgcn_rcpf(1.f + __expf(-x));
}

// ---- agent-scope (device-coherent, L2-bypassing) accessors for cross-phase data ----
__device__ __forceinline__ float agld(const float* p){
  return __hip_atomic_load(p, __ATOMIC_RELAXED, __HIP_MEMORY_SCOPE_AGENT);
}
__device__ __forceinline__ void agst(float* p, float v){
  __hip_atomic_store(p, v, __ATOMIC_RELAXED, __HIP_MEMORY_SCOPE_AGENT);
}
__device__ __forceinline__ f32x2 agld2(const float* p){
  unsigned long long u = __hip_atomic_load((const unsigned long long*)p,
                                           __ATOMIC_RELAXED, __HIP_MEMORY_SCOPE_AGENT);
  union { unsigned long long u; f32x2 f; } v; v.u = u; return v.f;
}
__device__ __forceinline__ void agst2(float* p, float a, float b){
  union { f32x2 f; unsigned long long u; } v; v.f.x = a; v.f.y = b;
  __hip_atomic_store((unsigned long long*)p, v.u, __ATOMIC_RELAXED, __HIP_MEMORY_SCOPE_AGENT);
}

// ---------------- P0: weight transposes (f32 -> bf16 NxK) + converts + pgen_emb ----------------
__device__ void transpose_bf16(const float* __restrict__ in, unsigned short* __restrict__ out,
                               int R, int C, int tile, float (*t)[65]){
  int tcn = C >> 6;
  int tr = tile / tcn, tc = tile - tr * tcn;
  int r0 = tr << 6, c0 = tc << 6;
  int cc = threadIdx.x & 63, rb = threadIdx.x >> 6;
  #pragma unroll
  for (int p = 0; p < 16; p++){
    int r = rb + p * 4;
    t[r][cc] = in[(size_t)(r0 + r) * C + (c0 + cc)];
  }
  __syncthreads();
  #pragma unroll
  for (int p = 0; p < 16; p++){
    int r = rb + p * 4;
    out[(size_t)(c0 + r) * R + (r0 + cc)] = f2bf(t[cc][r]);
  }
}

__global__ __launch_bounds__(256) void k_prep(
    const float* __restrict__ Wout, const float* __restrict__ Wg, const float* __restrict__ Ug,
    const float* __restrict__ W1, const float* __restrict__ W2, const float* __restrict__ enc,
    const float* __restrict__ dec_hidden, const int* __restrict__ dec_inp,
    const float* __restrict__ embedding, const float* __restrict__ Wp,
    unsigned short* WoutT, unsigned short* WgT, unsigned short* UgT,
    unsigned short* W1T, unsigned short* W2T, unsigned short* enc_bf,
    float* h0, unsigned short* h_bf, float* pgen_emb, unsigned* bar)
{
  __shared__ float tls[64][65];
  int b = blockIdx.x;
  int tid = threadIdx.x;
  if (b == 0 && tid < 64) bar[tid] = 0u;  // zero grid-barrier counter for k_mega (each replay)
  if (b < 4000){ transpose_bf16(Wout, WoutT, 512, 32000, b, tls); return; }
  b -= 4000;
  if (b < 288){ transpose_bf16(Wg, WgT, 768, 1536, b, tls); return; }
  b -= 288;
  if (b < 192){ transpose_bf16(Ug, UgT, 512, 1536, b, tls); return; }
  b -= 192;
  if (b < 64){ transpose_bf16(W1, W1T, 512, 512, b, tls); return; }
  b -= 64;
  if (b < 64){ transpose_bf16(W2, W2T, 512, 512, b, tls); return; }
  b -= 64;
  if (b < 3200){
    size_t i0 = (size_t)b * 2048 + tid;
    #pragma unroll
    for (int p = 0; p < 8; p++){ size_t i = i0 + p * 256; enc_bf[i] = f2bf(enc[i]); }
    return;
  }
  b -= 3200;
  if (b < 8){ // h0 = dec_hidden (f32 + bf16 copies)
    size_t i0 = (size_t)b * 2048 + tid;
    #pragma unroll
    for (int p = 0; p < 8; p++){
      size_t i = i0 + p * 256; float v = dec_hidden[i];
      h0[i] = v; h_bf[i] = f2bf(v);
    }
    return;
  }
  b -= 8;
  { // 40 blocks: pgen_emb[t][b] = emb(t,b) . Wp[1024:1280]
    int t = b;
    int bb = tid >> 3, l8 = tid & 7;
    int tok = dec_inp[bb * 41 + t];
    const float* e = embedding + (size_t)tok * 256 + l8 * 32;
    const float* wp = Wp + 1024 + l8 * 32;
    float p = 0.f;
    #pragma unroll
    for (int j = 0; j < 32; j++) p += e[j] * wp[j];
    p += __shfl_xor(p, 1); p += __shfl_xor(p, 2); p += __shfl_xor(p, 4);
    if (l8 == 0) pgen_emb[t * 32 + bb] = p;
  }
}

// ---------------- P1: embW[t,b,:] = emb(t,b) @ Wg[0:256,:] + bg   (all steps) ----------------
__global__ __launch_bounds__(256) void k_embw(
    const int* __restrict__ dec_inp, const float* __restrict__ embedding,
    const unsigned short* __restrict__ WgT, const float* __restrict__ bg,
    float* __restrict__ embW)
{
  __shared__ unsigned short as[64 * 264];
  int blk = blockIdx.x;         // 20 m-tiles x 24 n-tiles
  int bm = blk / 24, bn = blk - bm * 24;
  int m0 = bm * 64, n0 = bn * 64;
  int tid = threadIdx.x;
  for (int i = tid; i < 64 * 256; i += 256){
    int r = i >> 8, c = i & 255;
    int R = m0 + r; int t = R >> 5, bb = R & 31;
    int tok = dec_inp[bb * 41 + t];
    as[r * 264 + c] = f2bf(embedding[(size_t)tok * 256 + c]);
  }
  __syncthreads();
  int lane = tid & 63, w = tid >> 6;
  int l15 = lane & 15, quad = lane >> 4;
  const unsigned short* arow = as + (w * 16 + l15) * 264 + quad * 8;
  f32x4 acc[4];
  #pragma unroll
  for (int i = 0; i < 4; i++) acc[i] = (f32x4)0.0f;
  for (int k0 = 0; k0 < 256; k0 += 32){
    bf16x8 a = *(const bf16x8*)(arow + k0);
    #pragma unroll
    for (int nt = 0; nt < 4; nt++){
      const unsigned short* brow = WgT + (size_t)(n0 + nt * 16 + l15) * 768 + k0 + quad * 8;
      acc[nt] = __builtin_amdgcn_mfma_f32_16x16x32_bf16(a, *(const bf16x8*)brow, acc[nt], 0, 0, 0);
    }
  }
  #pragma unroll
  for (int nt = 0; nt < 4; nt++){
    int col = n0 + nt * 16 + l15;
    float bias = bg[col];
    #pragma unroll
    for (int r = 0; r < 4; r++){
      int row = m0 + w * 16 + quad * 4 + r;
      embW[(size_t)row * 1536 + col] = acc[nt][r] + bias;
    }
  }
}

// ---------------- P2: enc_feat = enc_output @ W2 + b2   (bf16 MFMA) ----------------
__global__ __launch_bounds__(256) void k_encfeat(
    const unsigned short* __restrict__ enc_bf, const unsigned short* __restrict__ W2T,
    const float* __restrict__ b2, unsigned short* __restrict__ ef_bf)
{
  int blk = blockIdx.x;            // 200 x 8
  int bm = blk >> 3, bn = blk & 7;
  int lane = threadIdx.x & 63, w = threadIdx.x >> 6;
  int l15 = lane & 15, quad = lane >> 4;
  int m0 = bm * 64 + w * 16;
  int n0 = bn * 64;
  const unsigned short* arow = enc_bf + (size_t)(m0 + l15) * 512 + quad * 8;
  f32x4 acc[4];
  #pragma unroll
  for (int i = 0; i < 4; i++) acc[i] = (f32x4)0.0f;
  for (int k0 = 0; k0 < 512; k0 += 32){
    bf16x8 a = *(const bf16x8*)(arow + k0);
    #pragma unroll
    for (int nt = 0; nt < 4; nt++){
      const unsigned short* brow = W2T + (size_t)(n0 + nt * 16 + l15) * 512 + k0 + quad * 8;
      acc[nt] = __builtin_amdgcn_mfma_f32_16x16x32_bf16(a, *(const bf16x8*)brow, acc[nt], 0, 0, 0);
    }
  }
  #pragma unroll
  for (int nt = 0; nt < 4; nt++){
    int col = n0 + nt * 16 + l15;
    float bias = b2[col];
    #pragma unroll
    for (int r = 0; r < 4; r++){
      int row = m0 + quad * 4 + r;
      ef_bf[(size_t)row * 512 + col] = f2bf(acc[nt][r] + bias);
    }
  }
}

// ========== round-0 standalone kernels for the PRE-decode state (verbatim) ==========

__global__ __launch_bounds__(256) void k_gemm_h(
    const unsigned short* __restrict__ h_bf,
    const unsigned short* __restrict__ WoutT, const float* __restrict__ bout, float* __restrict__ logits,
    const unsigned short* __restrict__ W1T, const float* __restrict__ b1, float* __restrict__ w1h,
    int nb_log, float* __restrict__ tilems,
    const int* __restrict__ eidx, const float* __restrict__ attn_prev,
    const float* __restrict__ pgens_prev, float* __restrict__ final_prev)
{
  int blk = blockIdx.x;
  int tid = threadIdx.x;
  if (blk >= nb_log + 8){ // scatter-add copy dist for PREVIOUS step
    int i = (blk - nb_log - 8) * 256 + tid;
    if (i >= 12800 || !final_prev) return;
    int b = i / 400;
    float wv = (1.f - pgens_prev[b]) * attn_prev[i];
    atomicAdd(final_prev + (size_t)b * VEXT + eidx[i], wv);
    return;
  }
  __shared__ unsigned short hs[32 * 520];
  __shared__ float smp[4][16][2];
  for (int i = tid; i < 8192; i += 256){
    int bb = i >> 8;
    int cp = (i & 255) * 2;
    *(unsigned int*)(hs + bb * 520 + cp) = *(const unsigned int*)(h_bf + bb * 512 + cp);
  }
  __syncthreads();
  int is_logits = (blk < nb_log);
  const unsigned short* Bm; const float* bias; float* out; int n0, ldo;
  if (is_logits){ Bm = WoutT; bias = bout; out = logits; n0 = blk * 64; ldo = VV; }
  else { Bm = W1T; bias = b1; out = w1h; n0 = (blk - nb_log) * 64; ldo = 512; }
  int lane = tid & 63, w = tid >> 6;
  int l15 = lane & 15, quad = lane >> 4;
  int mt = (w & 1) * 16;
  int nbase = n0 + (w >> 1) * 32;
  f32x4 acc[2];
  acc[0] = (f32x4)0.0f; acc[1] = (f32x4)0.0f;
  const unsigned short* arow = hs + (mt + l15) * 520 + quad * 8;
  #pragma unroll 2
  for (int k0 = 0; k0 < 512; k0 += 32){
    bf16x8 a = *(const bf16x8*)(arow + k0);
    #pragma unroll
    for (int s = 0; s < 2; s++){
      const unsigned short* br = Bm + (size_t)(nbase + s * 16 + l15) * 512 + k0 + quad * 8;
      acc[s] = __builtin_amdgcn_mfma_f32_16x16x32_bf16(a, *(const bf16x8*)br, acc[s], 0, 0, 0);
    }
  }
  float vv[2][4];
  #pragma unroll
  for (int s = 0; s < 2; s++){
    int col = nbase + s * 16 + l15;
    float bi = bias[col];
    #pragma unroll
    for (int r = 0; r < 4; r++){
      int row = mt + quad * 4 + r;
      vv[s][r] = acc[s][r] + bi;
      out[(size_t)row * ldo + col] = vv[s][r];
    }
  }
  if (is_logits){
    #pragma unroll
    for (int r = 0; r < 4; r++){
      float m = fmaxf(vv[0][r], vv[1][r]);
      m = fmaxf(m, __shfl_xor(m, 1)); m = fmaxf(m, __shfl_xor(m, 2));
      m = fmaxf(m, __shfl_xor(m, 4)); m = fmaxf(m, __shfl_xor(m, 8));
      float e = __expf(vv[0][r] - m) + __expf(vv[1][r] - m);
      e += __shfl_xor(e, 1); e += __shfl_xor(e, 2); e += __shfl_xor(e, 4); e += __shfl_xor(e, 8);
      if (l15 == 0){ smp[w][quad * 4 + r][0] = m; smp[w][quad * 4 + r][1] = e; }
    }
    __syncthreads();
    if (tid < 32){
      int half = tid >> 4, row = tid & 15;
      float ma = smp[half][row][0], mb = smp[half + 2][row][0];
      float M = fmaxf(ma, mb);
      float S = smp[half][row][1] * __expf(ma - M) + smp[half + 2][row][1] * __expf(mb - M);
      tilems[((size_t)blk * 32 + half * 16 + row) * 2] = M;
      tilems[((size_t)blk * 32 + half * 16 + row) * 2 + 1] = S;
    }
  }
}

__global__ __launch_bounds__(256) void k_score(
    const unsigned short* __restrict__ ef_bf, const float* __restrict__ w1h,
    const float* __restrict__ Wc, const float* __restrict__ Va, const float* __restrict__ bv,
    const float* __restrict__ cov, float* __restrict__ scores,
    const float* __restrict__ h_new, const float* __restrict__ Wp,
    float* __restrict__ pgen_hd)
{
  int blk = blockIdx.x;
  int tid = threadIdx.x;
  if (blk < 800){
    __shared__ float whs[512], wcs[512], vas[512];
    int b = blk / 25, lt = blk - b * 25;
    for (int i = tid; i < 512; i += 256){ whs[i] = w1h[b * 512 + i]; wcs[i] = Wc[i]; vas[i] = Va[i]; }
    __syncthreads();
    int li = tid >> 4;
    int a0 = (tid & 15) * 32;
    int l = lt * 16 + li;
    float covl = cov ? cov[b * 400 + l] : 0.f;
    const unsigned short* ef = ef_bf + (size_t)(b * 400 + l) * 512 + a0;
    float p = 0.f;
    #pragma unroll
    for (int i = 0; i < 32; i += 8){
      bf16x8 v8 = *(const bf16x8*)(ef + i);
      #pragma unroll
      for (int j = 0; j < 8; j++){
        int aa = a0 + i + j;
        float arg = whs[aa] + bf2f((unsigned short)v8[j]) + covl * wcs[aa];
        p += fast_tanh(arg) * vas[aa];
      }
    }
    p += __shfl_xor(p, 1); p += __shfl_xor(p, 2); p += __shfl_xor(p, 4); p += __shfl_xor(p, 8);
    if ((tid & 15) == 0) scores[b * 400 + l] = p + bv[0];
    return;
  }
  blk -= 800;
  {
    int b = blk;
    __shared__ float red[256];
    float p = 0.f;
    for (int i = tid; i < 512; i += 256) p += h_new[b * 512 + i] * Wp[512 + i];
    red[tid] = p; __syncthreads();
    for (int s = 128; s > 0; s >>= 1){ if (tid < s) red[tid] += red[tid + s]; __syncthreads(); }
    if (tid == 0) pgen_hd[b] = red[0];
  }
}

__global__ __launch_bounds__(256) void k_attn_ctx(
    const float* __restrict__ scores, const float* __restrict__ mask,
    const float* __restrict__ cov_in, float* attn_out, float* cov_out,
    const unsigned short* __restrict__ enc_bf,
    float* __restrict__ ctx_out, float* ctxf_out, const float* __restrict__ Wp,
    float* __restrict__ pgen_cn, float* __restrict__ pgen_co,
    const float* __restrict__ tilems, float* __restrict__ rowMS)
{
  int b = blockIdx.x >> 3, ct = blockIdx.x & 7;
  int tid = threadIdx.x;
  __shared__ float at[400];
  __shared__ float red[512];
  float mx = -1e30f;
  for (int i = tid; i < 400; i += 256){ float s = scores[b * 400 + i]; at[i] = s; mx = fmaxf(mx, s); }
  red[tid] = mx; __syncthreads();
  for (int s = 128; s > 0; s >>= 1){ if (tid < s) red[tid] = fmaxf(red[tid], red[tid + s]); __syncthreads(); }
  mx = red[0]; __syncthreads();
  float sm = 0.f;
  for (int i = tid; i < 400; i += 256){ float e = __expf(at[i] - mx) * mask[b * 400 + i]; at[i] = e; sm += e; }
  red[tid] = sm; __syncthreads();
  for (int s = 128; s > 0; s >>= 1){ if (tid < s) red[tid] += red[tid + s]; __syncthreads(); }
  float inv = __builtin_amdgcn_rcpf(red[0]);
  __syncthreads();
  for (int i = tid; i < 400; i += 256){
    float a = at[i] * inv; at[i] = a;
    if (ct == 0){
      if (attn_out) attn_out[b * 400 + i] = a;
      float cv = (cov_in ? cov_in[b * 400 + i] : 0.f) + a;
      if (cov_out) cov_out[b * 400 + i] = cv;
    }
  }
  __syncthreads();
  int colp = (tid & 31) * 2;
  int chunk = tid >> 5;
  const unsigned short* base = enc_bf + (size_t)b * 400 * 512 + ct * 64 + colp;
  float a0 = 0.f, a1 = 0.f;
  for (int i = 0; i < 50; i++){
    int l = chunk * 50 + i;
    unsigned int u = *(const unsigned int*)(base + (size_t)l * 512);
    float av = at[l];
    a0 += av * bf2f((unsigned short)(u & 0xffffu));
    a1 += av * bf2f((unsigned short)(u >> 16));
  }
  red[chunk * 64 + colp] = a0; red[chunk * 64 + colp + 1] = a1;
  __syncthreads();
  if (tid < 64){
    float s = 0.f;
    #pragma unroll
    for (int c = 0; c < 8; c++) s += red[c * 64 + tid];
    int col = ct * 64 + tid;
    ctx_out[b * 512 + col] = s;
    if (ctxf_out) ctxf_out[b * 512 + col] = s;
    float cn = s * Wp[col];
    float co = s * Wp[1280 + col];
    #pragma unroll
    for (int off = 32; off > 0; off >>= 1){ cn += __shfl_down(cn, off); co += __shfl_down(co, off); }
    if (tid == 0){ pgen_cn[b * 8 + ct] = cn; pgen_co[b * 8 + ct] = co; }
  }
  __syncthreads();
  if (ct == 0 && tilems != nullptr){
    float M = -1e30f;
    for (int i = tid; i < 500; i += 256) M = fmaxf(M, tilems[(i * 32 + b) * 2]);
    red[tid] = M; __syncthreads();
    for (int s = 128; s > 0; s >>= 1){ if (tid < s) red[tid] = fmaxf(red[tid], red[tid + s]); __syncthreads(); }
    M = red[0]; __syncthreads();
    float S = 0.f;
    for (int i = tid; i < 500; i += 256) S += tilems[(i * 32 + b) * 2 + 1] * __expf(tilems[(i * 32 + b) * 2] - M);
    red[tid] = S; __syncthreads();
    for (int s = 128; s > 0; s >>= 1){ if (tid < s) red[tid] += red[tid + s]; __syncthreads(); }
    if (tid == 0){ rowMS[b * 2] = M; rowMS[b * 2 + 1] = red[0]; }
  }
}

// ================= persistent mega-kernel (decode loop) =================
struct MP {
  const float* mask; const int* eidx;
  const float* Wc; const float* Va; const float* bv;
  const float* b1; const float* bout; const float* Wp; const float* bp;
  const unsigned short* WgT; const unsigned short* UgT;
  const unsigned short* W1T; const unsigned short* WoutT;
  const unsigned short* ef_bf; const unsigned short* enc_bf;
  const float* embW;
  float* logits; float* tilems; float* w1h; float* scores; float* rowMS;
  float* pgen_hd; float* pgen_cn; float* pgen_co0; float* pgen_co1;
  float* pgen_emb;
  float* hbuf0; float* hbuf1; float* ctxbuf0; float* ctxbuf1;
  float* final_; float* attns; float* covs; float* hf; float* ctxf; float* pgens;
  unsigned* bar;
};

// cache-op-free grid barrier: monotonic counter, relaxed RMW + relaxed poll.
// Correct because ALL cross-phase data uses agent-scope (sc1) accesses that hit
// the device coherence point, and the explicit waitcnt drains each wave's
// outstanding stores (acked at coherence point) before arrival.
__device__ __forceinline__ void gbar(unsigned* cnt, unsigned target)
{
  asm volatile("s_waitcnt vmcnt(0) lgkmcnt(0)" ::: "memory");
  __syncthreads();
  if (threadIdx.x == 0){
    __hip_atomic_fetch_add(cnt, 1u, __ATOMIC_RELAXED, __HIP_MEMORY_SCOPE_AGENT);
    while (__hip_atomic_load(cnt, __ATOMIC_RELAXED, __HIP_MEMORY_SCOPE_AGENT) < target)
      __builtin_amdgcn_s_sleep(4);
  }
  __syncthreads();
}

// ---------------- final-dist writer (leading sync guards s_pg reuse) ----------------
__device__ void final_dist_write(int f, int tid, const MP& P,
    const float* __restrict__ pgen_co, const float* __restrict__ pgen_emb_t,
    float* __restrict__ final_t, float* __restrict__ pgens_t)
{
  __shared__ float s_pg;
  __syncthreads();
  int b = f >> 4, vt = f & 15;
  if (tid == 0){
    float p = agld(P.pgen_hd + b) + pgen_emb_t[b] + P.bp[0];
    #pragma unroll
    for (int j = 0; j < 8; j++) p += agld(P.pgen_cn + b * 8 + j) + agld(pgen_co + b * 8 + j);
    float pg = fast_sigmoid(p);
    s_pg = pg;
    if (vt == 0) agst(pgens_t + b, pg);
  }
  __syncthreads();
  float pg = s_pg;
  float M = agld(P.rowMS + b * 2);
  float Sinv = __builtin_amdgcn_rcpf(agld(P.rowMS + b * 2 + 1));
  const float* lg = P.logits + (size_t)b * VV;
  float* dst = final_t + (size_t)b * VEXT;
  int v0 = vt * 2048 + tid * 8;
  if (v0 + 7 < VV){
    f32x2 x0 = agld2(lg + v0);
    f32x2 x1 = agld2(lg + v0 + 2);
    f32x2 x2 = agld2(lg + v0 + 4);
    f32x2 x3 = agld2(lg + v0 + 6);
    agst2(dst + v0,     pg * __expf(x0.x - M) * Sinv, pg * __expf(x0.y - M) * Sinv);
    agst2(dst + v0 + 2, pg * __expf(x1.x - M) * Sinv, pg * __expf(x1.y - M) * Sinv);
    agst2(dst + v0 + 4, pg * __expf(x2.x - M) * Sinv, pg * __expf(x2.y - M) * Sinv);
    agst2(dst + v0 + 6, pg * __expf(x3.x - M) * Sinv, pg * __expf(x3.y - M) * Sinv);
  } else {
    #pragma unroll
    for (int j = 0; j < 8; j++){
      int v = v0 + j;
      float val = (v < VV) ? pg * __expf(agld(lg + v) - M) * Sinv : 0.f;
      if (v < VEXT) agst(dst + v, val);
    }
  }
}

// ---------------- GRU step (blocks 0..7) ----------------
__device__ __forceinline__ void dev_gru(int blk, int tid, const MP& P,
    const float* __restrict__ ctx_old, const float* __restrict__ h_old,
    const float* __restrict__ embW_t,
    float* __restrict__ h_new, float* hf_out, unsigned short* xs)
{
  for (int i = tid; i < 32 * 512; i += 256){
    int bb = i >> 9, c = i & 511;
    xs[bb * 520 + c] = f2bf(agld(ctx_old + i));
  }
  __syncthreads();
  int lane = tid & 63, w = tid >> 6;
  int l15 = lane & 15, quad = lane >> 4;
  int mt = (w & 1) * 16;
  int n0 = blk * 64 + (w >> 1) * 32;
  f32x4 accZ[2], accR[2], accH[2], accU[2];
  #pragma unroll
  for (int s = 0; s < 2; s++){
    int col = n0 + s * 16 + l15;
    #pragma unroll
    for (int r = 0; r < 4; r++){
      int row = mt + quad * 4 + r;
      const float* e = embW_t + (size_t)row * 1536 + col;
      accZ[s][r] = e[0]; accR[s][r] = e[512]; accH[s][r] = e[1024];
      accU[s][r] = 0.f;
    }
  }
  for (int k0 = 0; k0 < 512; k0 += 32){
    bf16x8 a = *(const bf16x8*)(xs + (mt + l15) * 520 + k0 + quad * 8);
    #pragma unroll
    for (int s = 0; s < 2; s++){
      int col = n0 + s * 16 + l15;
      const unsigned short* bz = P.WgT + (size_t)col * 768 + 256 + k0 + quad * 8;
      const unsigned short* br = P.WgT + (size_t)(col + 512) * 768 + 256 + k0 + quad * 8;
      const unsigned short* bh = P.WgT + (size_t)(col + 1024) * 768 + 256 + k0 + quad * 8;
      accZ[s] = __builtin_amdgcn_mfma_f32_16x16x32_bf16(a, *(const bf16x8*)bz, accZ[s], 0, 0, 0);
      accR[s] = __builtin_amdgcn_mfma_f32_16x16x32_bf16(a, *(const bf16x8*)br, accR[s], 0, 0, 0);
      accH[s] = __builtin_amdgcn_mfma_f32_16x16x32_bf16(a, *(const bf16x8*)bh, accH[s], 0, 0, 0);
    }
  }
  __syncthreads();
  for (int i = tid; i < 32 * 512; i += 256){
    int bb = i >> 9, c = i & 511;
    xs[bb * 520 + c] = f2bf(agld(h_old + i));
  }
  __syncthreads();
  for (int k0 = 0; k0 < 512; k0 += 32){
    bf16x8 a = *(const bf16x8*)(xs + (mt + l15) * 520 + k0 + quad * 8);
    #pragma unroll
    for (int s = 0; s < 2; s++){
      int col = n0 + s * 16 + l15;
      const unsigned short* bz = P.UgT + (size_t)col * 512 + k0 + quad * 8;
      const unsigned short* br = P.UgT + (size_t)(col + 512) * 512 + k0 + quad * 8;
      const unsigned short* bh = P.UgT + (size_t)(col + 1024) * 512 + k0 + quad * 8;
      accZ[s] = __builtin_amdgcn_mfma_f32_16x16x32_bf16(a, *(const bf16x8*)bz, accZ[s], 0, 0, 0);
      accR[s] = __builtin_amdgcn_mfma_f32_16x16x32_bf16(a, *(const bf16x8*)br, accR[s], 0, 0, 0);
      accU[s] = __builtin_amdgcn_mfma_f32_16x16x32_bf16(a, *(const bf16x8*)bh, accU[s], 0, 0, 0);
    }
  }
  #pragma unroll
  for (int s = 0; s < 2; s++){
    int col = n0 + s * 16 + l15;
    #pragma unroll
    for (int r = 0; r < 4; r++){
      int bb = mt + quad * 4 + r;
      float z  = fast_sigmoid(accZ[s][r]);
      float rr = fast_sigmoid(accR[s][r]);
      float hh = fast_tanh(accH[s][r] + rr * accU[s][r]);
      float ho = agld(h_old + bb * 512 + col);
      float hn = z * ho + (1.f - z) * hh;
      agst(h_new + bb * 512 + col, hn);
      if (hf_out) hf_out[bb * 512 + col] = hn;
    }
  }
}

// ---- logits tile (u<500) or w1h tile (500<=u<508); stages h (f32) -> bf16 LDS ----
__device__ __forceinline__ void dev_gemm(int u, int tid, const MP& P, const float* __restrict__ h,
                                         unsigned short* hs, float* smp)
{
  for (int i = tid; i < 32 * 512; i += 256){
    int bb = i >> 9, c = i & 511;
    hs[bb * 520 + c] = f2bf(agld(h + i));
  }
  __syncthreads();
  int is_logits = (u < 500);
  const unsigned short* Bm; const float* bias; float* out; int n0, ldo;
  if (is_logits){ Bm = P.WoutT; bias = P.bout; out = P.logits; n0 = u * 64; ldo = VV; }
  else { Bm = P.W1T; bias = P.b1; out = P.w1h; n0 = (u - 500) * 64; ldo = 512; }
  int lane = tid & 63, w = tid >> 6;
  int l15 = lane & 15, quad = lane >> 4;
  int mt = (w & 1) * 16;
  int nbase = n0 + (w >> 1) * 32;
  f32x4 acc[2];
  acc[0] = (f32x4)0.0f; acc[1] = (f32x4)0.0f;
  const unsigned short* arow = hs + (mt + l15) * 520 + quad * 8;
  #pragma unroll 2
  for (int k0 = 0; k0 < 512; k0 += 32){
    bf16x8 a = *(const bf16x8*)(arow + k0);
    #pragma unroll
    for (int s = 0; s < 2; s++){
      const unsigned short* br = Bm + (size_t)(nbase + s * 16 + l15) * 512 + k0 + quad * 8;
      acc[s] = __builtin_amdgcn_mfma_f32_16x16x32_bf16(a, *(const bf16x8*)br, acc[s], 0, 0, 0);
    }
  }
  float vv[2][4];
  #pragma unroll
  for (int s = 0; s < 2; s++){
    int col = nbase + s * 16 + l15;
    float bi = bias[col];
    #pragma unroll
    for (int r = 0; r < 4; r++){
      int row = mt + quad * 4 + r;
      vv[s][r] = acc[s][r] + bi;
      agst(out + (size_t)row * ldo + col, vv[s][r]);
    }
  }
  if (is_logits){
    #pragma unroll
    for (int r = 0; r < 4; r++){
      float m = fmaxf(vv[0][r], vv[1][r]);
      m = fmaxf(m, __shfl_xor(m, 1)); m = fmaxf(m, __shfl_xor(m, 2));
      m = fmaxf(m, __shfl_xor(m, 4)); m = fmaxf(m, __shfl_xor(m, 8));
      float e = __expf(vv[0][r] - m) + __expf(vv[1][r] - m);
      e += __shfl_xor(e, 1); e += __shfl_xor(e, 2); e += __shfl_xor(e, 4); e += __shfl_xor(e, 8);
      if (l15 == 0){ smp[(w * 16 + quad * 4 + r) * 2] = m; smp[(w * 16 + quad * 4 + r) * 2 + 1] = e; }
    }
    __syncthreads();
    if (tid < 32){
      int half = tid >> 4, row = tid & 15;
      float ma = smp[(half * 16 + row) * 2],     mb = smp[((half + 2) * 16 + row) * 2];
      float M = fmaxf(ma, mb);
      float S = smp[(half * 16 + row) * 2 + 1] * __expf(ma - M)
              + smp[((half + 2) * 16 + row) * 2 + 1] * __expf(mb - M);
      agst(P.tilems + ((size_t)u * 32 + half * 16 + row) * 2, M);
      agst(P.tilems + ((size_t)u * 32 + half * 16 + row) * 2 + 1, S);
    }
  }
}

__device__ __forceinline__ void dev_scatter(int c, int tid, const MP& P,
    const float* __restrict__ attn_prev, const float* __restrict__ pgens_prev,
    float* __restrict__ final_prev)
{
  int i = c * 256 + tid;
  if (i >= 12800) return;
  int b = i / 400;
  float wv = (1.f - agld(pgens_prev + b)) * agld(attn_prev + i);
  atomicAdd(final_prev + (size_t)b * VEXT + P.eidx[i], wv);
}

__device__ __forceinline__ void dev_score(int u, int tid, const MP& P,
                                          const float* cov, float* sf)
{
  __syncthreads();
  float* whs = sf; float* wcs = sf + 512; float* vas = sf + 1024;
  int b = u / 25, lt = u - b * 25;
  for (int i = tid; i < 512; i += 256){ whs[i] = agld(P.w1h + b * 512 + i); wcs[i] = P.Wc[i]; vas[i] = P.Va[i]; }
  __syncthreads();
  int li = tid >> 4;
  int a0 = (tid & 15) * 32;
  int l = lt * 16 + li;
  float covl = cov ? agld(cov + b * 400 + l) : 0.f;
  const unsigned short* ef = P.ef_bf + (size_t)(b * 400 + l) * 512 + a0;
  float pv = 0.f;
  #pragma unroll
  for (int i = 0; i < 32; i += 8){
    bf16x8 v8 = *(const bf16x8*)(ef + i);
    #pragma unroll
    for (int j = 0; j < 8; j++){
      int aa = a0 + i + j;
      float arg = whs[aa] + bf2f((unsigned short)v8[j]) + covl * wcs[aa];
      pv += fast_tanh(arg) * vas[aa];
    }
  }
  pv += __shfl_xor(pv, 1); pv += __shfl_xor(pv, 2); pv += __shfl_xor(pv, 4); pv += __shfl_xor(pv, 8);
  if ((tid & 15) == 0) agst(P.scores + b * 400 + l, pv + P.bv[0]);
}

__device__ __forceinline__ void dev_pgen_hd(int b, int tid, const MP& P,
                                            const float* __restrict__ h, float* red)
{
  __syncthreads();
  float pv = 0.f;
  for (int i = tid; i < 512; i += 256) pv += agld(h + b * 512 + i) * P.Wp[512 + i];
  red[tid] = pv; __syncthreads();
  for (int s = 128; s > 0; s >>= 1){ if (tid < s) red[tid] += red[tid + s]; __syncthreads(); }
  if (tid == 0) agst(P.pgen_hd + b, red[0]);
}

__device__ __forceinline__ void dev_attn(int blk, int tid, const MP& P,
    const float* cov_in, float* attn_out, float* cov_out,
    float* __restrict__ ctx_out, float* ctxf_out, float* __restrict__ pgen_co_out,
    bool do_rowms, float* sf)
{
  __syncthreads();
  int b = blk >> 3, ct = blk & 7;
  float* at  = sf;            // [400]
  float* red = sf + 512;      // [512]
  float mx = -1e30f;
  for (int i = tid; i < 400; i += 256){ float s = agld(P.scores + b * 400 + i); at[i] = s; mx = fmaxf(mx, s); }
  red[tid] = mx; __syncthreads();
  for (int s = 128; s > 0; s >>= 1){ if (tid < s) red[tid] = fmaxf(red[tid], red[tid + s]); __syncthreads(); }
  mx = red[0]; __syncthreads();
  float sm = 0.f;
  for (int i = tid; i < 400; i += 256){ float e = __expf(at[i] - mx) * P.mask[b * 400 + i]; at[i] = e; sm += e; }
  red[tid] = sm; __syncthreads();
  for (int s = 128; s > 0; s >>= 1){ if (tid < s) red[tid] += red[tid + s]; __syncthreads(); }
  float inv = __builtin_amdgcn_rcpf(red[0]);
  __syncthreads();
  for (int i = tid; i < 400; i += 256){
    float a = at[i] * inv; at[i] = a;
    if (ct == 0){
      if (attn_out) agst(attn_out + b * 400 + i, a);
      float cv = (cov_in ? agld(cov_in + b * 400 + i) : 0.f) + a;
      if (cov_out) agst(cov_out + b * 400 + i, cv);
    }
  }
  __syncthreads();
  int colp = (tid & 31) * 2;
  int chunk = tid >> 5;
  const unsigned short* base = P.enc_bf + (size_t)b * 400 * 512 + ct * 64 + colp;
  float a0 = 0.f, a1 = 0.f;
  for (int i = 0; i < 50; i++){
    int l = chunk * 50 + i;
    unsigned int uu = *(const unsigned int*)(base + (size_t)l * 512);
    float av = at[l];
    a0 += av * bf2f((unsigned short)(uu & 0xffffu));
    a1 += av * bf2f((unsigned short)(uu >> 16));
  }
  red[chunk * 64 + colp] = a0; red[chunk * 64 + colp + 1] = a1;
  __syncthreads();
  if (tid < 64){
    float s = 0.f;
    #pragma unroll
    for (int c = 0; c < 8; c++) s += red[c * 64 + tid];
    int col = ct * 64 + tid;
    agst(ctx_out + b * 512 + col, s);
    if (ctxf_out) ctxf_out[b * 512 + col] = s;
    float cn = s * P.Wp[col];
    float co = s * P.Wp[1280 + col];
    #pragma unroll
    for (int off = 32; off > 0; off >>= 1){ cn += __shfl_down(cn, off); co += __shfl_down(co, off); }
    if (tid == 0){ agst(P.pgen_cn + b * 8 + ct, cn); agst(pgen_co_out + b * 8 + ct, co); }
  }
  __syncthreads();
  if (do_rowms && ct == 0){
    float M = -1e30f;
    for (int i = tid; i < 500; i += 256) M = fmaxf(M, agld(P.tilems + (i * 32 + b) * 2));
    red[tid] = M; __syncthreads();
    for (int s = 128; s > 0; s >>= 1){ if (tid < s) red[tid] = fmaxf(red[tid], red[tid + s]); __syncthreads(); }
    M = red[0]; __syncthreads();
    float S = 0.f;
    for (int i = tid; i < 500; i += 256)
      S += agld(P.tilems + (i * 32 + b) * 2 + 1) * __expf(agld(P.tilems + (i * 32 + b) * 2) - M);
    red[tid] = S; __syncthreads();
    for (int s = 128; s > 0; s >>= 1){ if (tid < s) red[tid] += red[tid + s]; __syncthreads(); }
    if (tid == 0){ agst(P.rowMS + b * 2, M); agst(P.rowMS + b * 2 + 1, red[0]); }
  }
}

__global__ __launch_bounds__(256, 2) void k_mega(MP P)
{
  __shared__ unsigned short s_u16[32 * 520];
  __shared__ float s_f[1552];
  __shared__ float s_smp[4 * 16 * 2];
  int blk = blockIdx.x, tid = threadIdx.x;
  unsigned tgt = 0;

  for (int t = 0; t < 40; t++){
    const int p = t & 1;
    float* h_old  = p ? P.hbuf1 : P.hbuf0;
    float* h_new  = p ? P.hbuf0 : P.hbuf1;
    float* c_old  = p ? P.ctxbuf1 : P.ctxbuf0;
    float* c_new  = p ? P.ctxbuf0 : P.ctxbuf1;
    float* co_cur = p ? P.pgen_co1 : P.pgen_co0;

    // ---- phase A: GRU(t) + final(t-1) ----
    if (blk < 8){
      dev_gru(blk, tid, P, c_old, h_old, P.embW + (size_t)t * 32 * 1536,
              h_new, (t == 39) ? P.hf : nullptr, s_u16);
    } else if (t >= 1){
      for (int f = blk - 8; f < 512; f += 504)
        final_dist_write(f, tid, P, co_cur, P.pgen_emb + (t - 1) * 32,
                         P.final_ + (size_t)(t - 1) * 32 * VEXT, P.pgens + (t - 1) * 32);
    }
    tgt += NBLK; gbar(P.bar, tgt);

    // ---- phase B: logits(t) + w1h(t) + scatter(t-1) ----
    if (blk < 508) dev_gemm(blk, tid, P, h_new, s_u16, s_smp);
    if (t >= 1){
      const float* attn_prev  = P.attns + (size_t)(t - 1) * 12800;
      const float* pgens_prev = P.pgens + (t - 1) * 32;
      float* final_prev = P.final_ + (size_t)(t - 1) * 32 * VEXT;
      if (blk >= 508) dev_scatter(blk - 508, tid, P, attn_prev, pgens_prev, final_prev);
      if (blk < 46)   dev_scatter(blk + 4,   tid, P, attn_prev, pgens_prev, final_prev);
    }
    tgt += NBLK; gbar(P.bar, tgt);

    // ---- phase C: scores(t) + pgen_hd(t) ----
    {
      const float* cov_t = P.covs + (size_t)t * 12800;
      dev_score(blk, tid, P, cov_t, s_f);
      if (blk < 320){
        int u2 = blk + 512;
        if (u2 < 800) dev_score(u2, tid, P, cov_t, s_f);
        else dev_pgen_hd(u2 - 800, tid, P, h_new, s_f);
      }
    }
    tgt += NBLK; gbar(P.bar, tgt);

    // ---- phase D: attn(t) softmax + context + pgen dots + rowMS ----
    if (blk < 256)
      dev_attn(blk, tid, P, P.covs + (size_t)t * 12800,
               (t < 39) ? P.attns + (size_t)(t + 1) * 12800 : nullptr,
               (t < 39) ? P.covs + (size_t)(t + 1) * 12800 : nullptr,
               c_new, (t == 39) ? P.ctxf : nullptr, co_cur, true, s_f);
    tgt += NBLK; gbar(P.bar, tgt);
  }

  // ---- epilogue: final(39) + scatter(39) ----
  final_dist_write(blk, tid, P, P.pgen_co0, P.pgen_emb + 39 * 32,
                   P.final_ + (size_t)39 * 32 * VEXT, P.pgens + 39 * 32);
  tgt += NBLK; gbar(P.bar, tgt);
  if (blk < 50) dev_scatter(blk, tid, P, P.attns + (size_t)39 * 12800,
                            P.pgens + 39 * 32, P.final_ + (size_t)39 * 32 * VEXT);
}

extern "C" void kernel_launch(void* const* d_in, const int* in_sizes, int n_in,
                              void* d_out, int out_size, void* d_ws, size_t ws_size,
                              hipStream_t stream) {
  const int*   dec_inp    = (const int*)d_in[0];
  const int*   eidx       = (const int*)d_in[1];
  const float* mask       = (const float*)d_in[2];
  const float* enc        = (const float*)d_in[4];
  const float* dec_hidden = (const float*)d_in[5];
  const float* embedding  = (const float*)d_in[6];
  const float* W1  = (const float*)d_in[7];
  const float* b1  = (const float*)d_in[8];
  const float* W2  = (const float*)d_in[9];
  const float* b2  = (const float*)d_in[10];
  const float* Wc  = (const float*)d_in[11];
  const float* Va  = (const float*)d_in[12];
  const float* bv  = (const float*)d_in[13];
  const float* Wg  = (const float*)d_in[14];
  const float* Ug  = (const float*)d_in[15];
  const float* bg  = (const float*)d_in[16];
  const float* Wout = (const float*)d_in[17];
  const float* bout = (const float*)d_in[18];
  const float* Wp  = (const float*)d_in[19];
  const float* bp  = (const float*)d_in[20];

  float* out    = (float*)d_out;
  float* final_ = out;                               // 40*32*32050
  float* attns  = out + (size_t)40 * 32 * VEXT;      // 40*32*400
  float* covs   = attns + 512000;
  float* hf     = covs + 512000;
  float* ctxf   = hf + 16384;
  float* pgens  = ctxf + 16384;

  char* wsb = (char*)d_ws; size_t off = 0;
  auto A = [&](size_t bytes)->char*{ char* p = wsb + off; off += (bytes + 255) & ~(size_t)255; return p; };
  float* logits   = (float*)A((size_t)32 * VV * 4);
  float* embW     = (float*)A((size_t)40 * 32 * 1536 * 4);
  float* tilems   = (float*)A(500 * 32 * 2 * 4);
  float* hbuf0    = (float*)A(65536);
  float* hbuf1    = (float*)A(65536);
  float* ctxbuf0  = (float*)A(65536);
  float* ctxbuf1  = (float*)A(65536);
  float* w1h      = (float*)A(65536);
  float* scores   = (float*)A(51200);
  float* rowMS    = (float*)A(256);
  float* pgen_hd  = (float*)A(128);
  float* pgen_cn  = (float*)A(1024);
  float* pgen_co0 = (float*)A(1024);
  float* pgen_co1 = (float*)A(1024);
  float* pgen_emb = (float*)A(40 * 32 * 4);
  unsigned* barm  = (unsigned*)A(256);
  unsigned short* h_bf   = (unsigned short*)A(32768);
  unsigned short* enc_bf = (unsigned short*)A((size_t)32 * 400 * 512 * 2);
  unsigned short* ef_bf  = (unsigned short*)A((size_t)32 * 400 * 512 * 2);
  unsigned short* W2T    = (unsigned short*)A(524288);
  unsigned short* W1T    = (unsigned short*)A(524288);
  unsigned short* WgT    = (unsigned short*)A(2359296);
  unsigned short* UgT    = (unsigned short*)A(1572864);
  unsigned short* WoutT  = (unsigned short*)A((size_t)VV * 512 * 2);

  // ---- prologue (parallel-wide prep; zeroes barrier counter each replay) ----
  k_prep<<<7856, 256, 0, stream>>>(Wout, Wg, Ug, W1, W2, enc, dec_hidden, dec_inp, embedding, Wp,
                                   WoutT, WgT, UgT, W1T, W2T, enc_bf, hbuf0, h_bf, pgen_emb, barm);
  k_embw<<<480, 256, 0, stream>>>(dec_inp, embedding, WgT, bg, embW);
  k_encfeat<<<1600, 256, 0, stream>>>(enc_bf, W2T, b2, ef_bf);

  // ---- round-0 pre-decode kernels (bit-identical initial state) ----
  k_gemm_h<<<8, 256, 0, stream>>>(h_bf, WoutT, bout, logits, W1T, b1, w1h, 0, tilems,
                                  eidx, nullptr, nullptr, nullptr); // w1h(h0) only
  k_score<<<832, 256, 0, stream>>>(ef_bf, w1h, Wc, Va, bv, nullptr, scores,
                                   hbuf0, Wp, pgen_hd);
  k_attn_ctx<<<256, 256, 0, stream>>>(scores, mask, nullptr, attns, covs, enc_bf,
                                      ctxbuf0, nullptr, Wp, pgen_cn, pgen_co1,
                                      nullptr, rowMS);

  // ---- persistent decode loop (regular launch; 512 blocks = 2/CU co-resident) ----
  MP mp;
  mp.mask = mask; mp.eidx = eidx;
  mp.Wc = Wc; mp.Va = Va; mp.bv = bv;
  mp.b1 = b1; mp.bout = bout; mp.Wp = Wp; mp.bp = bp;
  mp.WgT = WgT; mp.UgT = UgT; mp.W1T = W1T; mp.WoutT = WoutT;
  mp.ef_bf = ef_bf; mp.enc_bf = enc_bf;
  mp.embW = embW;
  mp.logits = logits; mp.tilems = tilems; mp.w1h = w1h; mp.scores = scores; mp.rowMS = rowMS;
  mp.pgen_hd = pgen_hd; mp.pgen_cn = pgen_cn; mp.pgen_co0 = pgen_co0; mp.pgen_co1 = pgen_co1;
  mp.pgen_emb = pgen_emb;
  mp.hbuf0 = hbuf0; mp.hbuf1 = hbuf1; mp.ctxbuf0 = ctxbuf0; mp.ctxbuf1 = ctxbuf1;
  mp.final_ = final_; mp.attns = attns; mp.covs = covs; mp.hf = hf; mp.ctxf = ctxf; mp.pgens = pgens;
  mp.bar = barm;
  k_mega<<<dim3(NBLK), dim3(256), 0, stream>>>(mp);
}